// Round 2
// baseline (1455.590 us; speedup 1.0000x reference)
//
#include <hip/hip_runtime.h>
#include <stdint.h>

#define M_DIM 8192
#define N_DIM 11008
#define K_DIM 4096
#define KP    2048      // K/2 int32 per packed-W row
#define NG    32        // scale groups per row (K/128)
#define BM    128
#define BN    128
#define BK    32
#define KSTEPS (K_DIM / BK)   // 128
#define NWG   ((N_DIM / BN) * (M_DIM / BM))   // 86*64 = 5504, divisible by 8

typedef __attribute__((ext_vector_type(2))) _Float16 half2v;
typedef __attribute__((ext_vector_type(8))) _Float16 half8;   // MFMA A/B frag (4 VGPRs)
typedef __attribute__((ext_vector_type(4))) float    floatx4; // MFMA C/D frag
typedef __attribute__((ext_vector_type(4))) int      intx4;
typedef __attribute__((ext_vector_type(4))) unsigned uintx4;

// 16-byte global -> LDS direct (wave-uniform LDS base + lane*16; per-lane global src)
#define GLD16(gptr, lptr)                                                        \
    __builtin_amdgcn_global_load_lds(                                            \
        (const __attribute__((address_space(1))) void*)(gptr),                   \
        (__attribute__((address_space(3))) void*)(lptr), 16, 0, 0)

// ---------------- pre-pass 1: X fp32 -> fp16 (exact: values originated fp16) --
__global__ __launch_bounds__(256)
void cvt_a(const float* __restrict__ X, _Float16* __restrict__ Aw)
{
    const size_t total  = (size_t)M_DIM * K_DIM / 8;   // 4,194,304 chunks of 8
    const size_t stride = (size_t)gridDim.x * 256;
    for (size_t i = (size_t)blockIdx.x * 256 + threadIdx.x; i < total; i += stride) {
        const float* src = X + i * 8;
        floatx4 x0 = *(const floatx4*)src;
        floatx4 x1 = *(const floatx4*)(src + 4);
        uintx4 o;
        o[0] = __builtin_bit_cast(unsigned, __builtin_amdgcn_cvt_pkrtz(x0[0], x0[1]));
        o[1] = __builtin_bit_cast(unsigned, __builtin_amdgcn_cvt_pkrtz(x0[2], x0[3]));
        o[2] = __builtin_bit_cast(unsigned, __builtin_amdgcn_cvt_pkrtz(x1[0], x1[1]));
        o[3] = __builtin_bit_cast(unsigned, __builtin_amdgcn_cvt_pkrtz(x1[2], x1[3]));
        *(uintx4*)(Aw + i * 8) = o;
    }
}

// ---------------- pre-pass 2: W int4 -> fp16 dequant --------------------------
// bit-trick: (0x6400 | q) is fp16 (1024+q); (1024+q)-1032 = q-8 exact; * s = one
// fp16-rounded multiply == reference (wq-8)*s and == old kernel's fp32-fma path.
__global__ __launch_bounds__(256)
void dequant_w(const int* __restrict__ Wp, const float* __restrict__ Sc,
               _Float16* __restrict__ Bw)
{
    const size_t total  = (size_t)N_DIM * (KP / 4);    // 5,636,096 chunks of 4 int32
    const size_t stride = (size_t)gridDim.x * 256;
    const half2v k1032  = {(_Float16)1032.0f, (_Float16)1032.0f};
    for (size_t c = (size_t)blockIdx.x * 256 + threadIdx.x; c < total; c += stride) {
        const int n   = (int)(c >> 9);          // c / (KP/4)
        const int kp0 = ((int)c & 511) << 2;    // 4-aligned, never crosses a group
        intx4 p = *(const intx4*)(Wp + (size_t)n * KP + kp0);
        const _Float16 s = (_Float16)Sc[n * NG + (kp0 >> 6)];   // exact fp16 recovery
        const half2v s2 = {s, s};
        uintx4 o;
#pragma unroll
        for (int i = 0; i < 4; ++i) {
            unsigned v = (unsigned)p[i];
            unsigned u = 0x64006400u | (v & 0xFu) | ((v & 0xF0u) << 12);
            half2v h = __builtin_bit_cast(half2v, u);   // (1024+lo, 1024+hi)
            h = (h - k1032) * s2;                       // (lo-8, hi-8) * s, one rounding
            o[i] = __builtin_bit_cast(unsigned, h);     // lo = even k, hi = odd k
        }
        *(uintx4*)(Bw + (size_t)n * K_DIM + (size_t)kp0 * 2) = o;
    }
}

// ---------------- main GEMM: m97 structure (fp16, global_load_lds w=16) -------
__global__ __launch_bounds__(256, 2)
void gemm_f16(const _Float16* __restrict__ A, const _Float16* __restrict__ B,
              float* __restrict__ Out)
{
    __shared__ __align__(16) _Float16 Al[BM * BK];   // 8 KB
    __shared__ __align__(16) _Float16 Bl[BN * BK];   // 8 KB

    const int tid  = threadIdx.x;
    const int lane = tid & 63;
    const int wave = tid >> 6;

    // XCD-aware swizzle: NWG % 8 == 0 -> simple form is bijective.
    // bm fastest: 64 consecutive ids on one XCD share a B panel (L2 reuse).
    const int b   = blockIdx.x;
    const int swz = (b & 7) * (NWG / 8) + (b >> 3);
    const int bm  = swz & 63;
    const int bn  = swz >> 6;

    // staging map: inst i (0/1), wave w, lane l -> row i*64 + w*16 + l/4,
    // col (l&3)*8 fp16.  LDS linear offset = (i*4+w)*1024B + l*16B == row*64B+col*2B.
    const int srow = wave * 16 + (lane >> 2);
    const int scol = (lane & 3) * 8;
    const _Float16* ga = A + (size_t)(bm * BM + srow) * K_DIM + scol;
    const _Float16* gb = B + (size_t)(bn * BN + srow) * K_DIM + scol;
    _Float16* la = Al + wave * 512;   // + 2048 for inst 1
    _Float16* lb = Bl + wave * 512;

    // MFMA fragment addressing (16x16x32, m89/m91-verified mapping)
    const int l16  = lane & 15;
    const int quad = lane >> 4;
    const int wm   = (wave >> 1) * 64;
    const int wn   = (wave & 1) * 64;
    const _Float16* Ar = Al + (wm + l16) * BK + quad * 8;
    const _Float16* Br = Bl + (wn + l16) * BK + quad * 8;

    floatx4 acc[4][4];
#pragma unroll
    for (int i = 0; i < 4; ++i)
#pragma unroll
        for (int j = 0; j < 4; ++j)
            acc[i][j] = (floatx4){0.f, 0.f, 0.f, 0.f};

    for (int ks = 0; ks < KSTEPS; ++ks) {
        __syncthreads();   // previous iteration's LDS reads complete
        const _Float16* gak = ga + ks * BK;
        const _Float16* gbk = gb + ks * BK;
        GLD16(gak,                         la);
        GLD16(gak + (size_t)64 * K_DIM,    la + 2048);
        GLD16(gbk,                         lb);
        GLD16(gbk + (size_t)64 * K_DIM,    lb + 2048);
        __syncthreads();   // compiler emits s_waitcnt vmcnt(0) before barrier

        half8 af[4], bf[4];
#pragma unroll
        for (int i = 0; i < 4; ++i) {
            af[i] = *(const half8*)(Ar + i * 16 * BK);
            bf[i] = *(const half8*)(Br + i * 16 * BK);
        }
#pragma unroll
        for (int mi = 0; mi < 4; ++mi)
#pragma unroll
            for (int ni = 0; ni < 4; ++ni)
                acc[mi][ni] = __builtin_amdgcn_mfma_f32_16x16x32_f16(
                    af[mi], bf[ni], acc[mi][ni], 0, 0, 0);
    }

    // epilogue: C/D col(n) = lane&15, row(m) = quad*4 + reg; fp32 out
    const int row0 = bm * BM + wm + quad * 4;
    const int col0 = bn * BN + wn + l16;
#pragma unroll
    for (int mi = 0; mi < 4; ++mi) {
#pragma unroll
        for (int r = 0; r < 4; ++r) {
            const size_t row = (size_t)(row0 + mi * 16 + r);
            float* orow = Out + row * N_DIM + col0;
#pragma unroll
            for (int ni = 0; ni < 4; ++ni)
                orow[ni * 16] = acc[mi][ni][r];
        }
    }
}

// ---------------- fallback: previous harness-verified kernel ------------------
__global__ __launch_bounds__(256, 2)
void w4a16_gemm(const float* __restrict__ X, const int* __restrict__ Wp,
                const float* __restrict__ Sc, float* __restrict__ Out)
{
    __shared__ __align__(16) _Float16 Alds[BM * BK];
    __shared__ __align__(16) _Float16 Blds[BN * BK];

    const int tid = threadIdx.x;
    const int bn  = blockIdx.x;
    const int bm  = blockIdx.y;

    const int srow  = tid >> 1;
    const int shalf = tid & 1;

    const float* Ag = X + (size_t)(bm * BM + srow) * K_DIM + shalf * 16;
    _Float16* Al = Alds + srow * BK + shalf * 16;

    const int gn = bn * BN + srow;
    const int* Bg = Wp + (size_t)gn * KP + shalf * 8;
    const float* Srow = Sc + (size_t)gn * NG;
    _Float16* Bl = Blds + srow * BK + shalf * 16;

    const int lane = tid & 63;
    const int wave = tid >> 6;
    const int wm   = (wave >> 1) * 64;
    const int wn   = (wave & 1) * 64;
    const int l16  = lane & 15;
    const int quad = lane >> 4;

    const _Float16* Ar = Alds + (wm + l16) * BK + quad * 8;
    const _Float16* Br = Blds + (wn + l16) * BK + quad * 8;

    floatx4 acc[4][4];
#pragma unroll
    for (int i = 0; i < 4; ++i)
#pragma unroll
        for (int j = 0; j < 4; ++j)
            acc[i][j] = (floatx4){0.f, 0.f, 0.f, 0.f};

    floatx4 ax[4];
#pragma unroll
    for (int i = 0; i < 4; ++i) ax[i] = *(const floatx4*)(Ag + i * 4);
    intx4 bp0 = *(const intx4*)Bg;
    intx4 bp1 = *(const intx4*)(Bg + 4);
    float sc  = Srow[0];

    for (int ks = 0; ks < KSTEPS; ++ks) {
        __syncthreads();

        _Float16 ab[16];
#pragma unroll
        for (int i = 0; i < 4; ++i) {
#pragma unroll
            for (int j = 0; j < 4; ++j)
                ab[4 * i + j] = (_Float16)ax[i][j];
        }
        ((intx4*)Al)[0] = ((const intx4*)ab)[0];
        ((intx4*)Al)[1] = ((const intx4*)ab)[1];

        const float s8 = sc * 8.0f;
        _Float16 wb[16];
#pragma unroll
        for (int i = 0; i < 4; ++i) {
            unsigned p = (unsigned)bp0[i];
            wb[2 * i + 0] = (_Float16)fmaf((float)(p & 0xFu), sc, -s8);
            wb[2 * i + 1] = (_Float16)fmaf((float)((p >> 4) & 0xFu), sc, -s8);
        }
#pragma unroll
        for (int i = 0; i < 4; ++i) {
            unsigned p = (unsigned)bp1[i];
            wb[8 + 2 * i + 0] = (_Float16)fmaf((float)(p & 0xFu), sc, -s8);
            wb[8 + 2 * i + 1] = (_Float16)fmaf((float)((p >> 4) & 0xFu), sc, -s8);
        }
        ((intx4*)Bl)[0] = ((const intx4*)wb)[0];
        ((intx4*)Bl)[1] = ((const intx4*)wb)[1];

        if (ks + 1 < KSTEPS) {
            const float* Agn = Ag + (ks + 1) * BK;
#pragma unroll
            for (int i = 0; i < 4; ++i) ax[i] = *(const floatx4*)(Agn + i * 4);
            const int* Bgn = Bg + (ks + 1) * (BK / 2);
            bp0 = *(const intx4*)Bgn;
            bp1 = *(const intx4*)(Bgn + 4);
            sc  = Srow[(ks + 1) >> 2];
        }

        __syncthreads();

        half8 af[4], bfr[4];
#pragma unroll
        for (int i = 0; i < 4; ++i) {
            af[i]  = *(const half8*)(Ar + i * 16 * BK);
            bfr[i] = *(const half8*)(Br + i * 16 * BK);
        }
#pragma unroll
        for (int mi = 0; mi < 4; ++mi)
#pragma unroll
            for (int ni = 0; ni < 4; ++ni)
                acc[mi][ni] = __builtin_amdgcn_mfma_f32_16x16x32_f16(
                    af[mi], bfr[ni], acc[mi][ni], 0, 0, 0);
    }

    const int row0 = bm * BM + wm + quad * 4;
    const int col0 = bn * BN + wn + l16;
#pragma unroll
    for (int mi = 0; mi < 4; ++mi) {
#pragma unroll
        for (int r = 0; r < 4; ++r) {
            const size_t row = (size_t)(row0 + mi * 16 + r);
            float* orow = Out + row * N_DIM + col0;
#pragma unroll
            for (int ni = 0; ni < 4; ++ni)
                orow[ni * 16] = acc[mi][ni][r];
        }
    }
}

extern "C" void kernel_launch(void* const* d_in, const int* in_sizes, int n_in,
                              void* d_out, int out_size, void* d_ws, size_t ws_size,
                              hipStream_t stream) {
    const float* X   = (const float*)d_in[0];
    const int*   Wp  = (const int*)d_in[1];
    const float* Sc  = (const float*)d_in[2];
    float*       Out = (float*)d_out;

    const size_t A_BYTES = (size_t)M_DIM * K_DIM * sizeof(_Float16);  // 64 MiB
    const size_t B_BYTES = (size_t)N_DIM * K_DIM * sizeof(_Float16);  // 86 MiB

    if (d_ws && ws_size >= A_BYTES + B_BYTES) {
        _Float16* Aw = (_Float16*)d_ws;
        _Float16* Bw = (_Float16*)((char*)d_ws + A_BYTES);
        cvt_a<<<2048, 256, 0, stream>>>(X, Aw);
        dequant_w<<<2048, 256, 0, stream>>>(Wp, Sc, Bw);
        gemm_f16<<<dim3(NWG), dim3(256), 0, stream>>>(Aw, Bw, Out);
    } else {
        // workspace too small: previous harness-verified kernel, unchanged
        dim3 grid(N_DIM / BN, M_DIM / BM);
        w4a16_gemm<<<grid, dim3(256), 0, stream>>>(X, Wp, Sc, Out);
    }
}